// Round 14
// baseline (548.642 us; speedup 1.0000x reference)
//
#include <hip/hip_runtime.h>

// Seq2Seq LSTM (enc 512 + dec 256 steps), H=50, B=2048, in/out dim 1.
//
// Round-14: r13 skeleton (MB=4, 512 blocks = 2/CU, gate-complete waves, one
// barrier/step, bf16-split MFMA) with the split terms PACKED INTO THE M
// ROWS. r13 was ~52% MFMA-pipe-bound at 96 MFMAs/block-step (M-rows 4/16
// useful x 3 cross-term MFMAs). Here A rows 0-3 = h_hi(b0..3), rows 4-7 =
// h_lo(b0..3), rows 8-15 dup; accumulating BOTH B=w_hi and B=w_lo into one
// D gives rows b / 4+b whose sum = (w_hi+w_lo)(h_hi+h_lo) EXACTLY (4-term,
// strictly better than r13's 3-term). Per gate per k-tile: 2 MFMAs -> 16
// per wave-step (was 24); A-frag reads 2 (was 4). MFMA-pipe/CU-step
// 931 -> 621 cyc.
// Row-sum: lane's batch = kg; keep = ac[kg], send = ac[kg^1] (3 cndmask
// each) then preact = keep + shfl_xor(send, 16)  [kg0<->kg1, kg2<->kg3;
// rows 8-15 duplicate rows 0-7 so kg2/3 pairs are consistent].
// Bias + wx*x are pre-masked to h_hi rows only (kg even) via bb/wx *= 0 on
// odd kg at load time -- no per-step select.
//
// Fragments (verified r10-r13): A[m=lane&15][k=(lane>>4)*8+j],
// B[n=lane&15][k], D row=4*(lane>>4)+reg, col=lane&15.
// L2E folded into weights/bias (gate g doubled -> tanh via sigm).

#define HID 50
#define SEQ 512
#define TGT 256
#define MB  4
#define L2E 1.44269504088896341f

typedef __attribute__((ext_vector_type(8))) short short8;
typedef __attribute__((ext_vector_type(4))) float f32x4;

__device__ __forceinline__ unsigned short f2bf(float f) {   // RNE fp32->bf16
    unsigned u = __float_as_uint(f);
    return (unsigned short)((u + 0x7fffu + ((u >> 16) & 1u)) >> 16);
}
__device__ __forceinline__ float bf2f(unsigned short b) {
    return __uint_as_float(((unsigned)b) << 16);
}
__device__ __forceinline__ float sigm2(float a) {   // a pre-scaled by L2E
    return __builtin_amdgcn_rcpf(1.0f + __builtin_amdgcn_exp2f(-a));
}
__device__ __forceinline__ float tanhc(float c) {   // c in linear domain
    return fmaf(2.0f,
        __builtin_amdgcn_rcpf(1.0f + __builtin_amdgcn_exp2f(-2.0f * L2E * c)),
        -1.0f);
}

#define MFMA(A, B, C) __builtin_amdgcn_mfma_f32_16x16x32_bf16((A), (B), (C), 0, 0, 0)

// h layout: block (split s, k-tile kt, k-octet qg) = 4 batches x 8 k shorts.
#define HB(s, kt, qg) ((((s) * 2 + (kt)) * 4 + (qg)) * 32)
#define HFSZ (2 * 2 * 4 * 32)   // 512 shorts

// Select my-batch / partner-batch regs (batch = kg, partner = kg^1).
#define SELK(ac) (k2 ? (k1 ? (ac)[3] : (ac)[2]) : (k1 ? (ac)[1] : (ac)[0]))
#define SELS(ac) (k2 ? (k1 ? (ac)[2] : (ac)[3]) : (k1 ? (ac)[0] : (ac)[1]))

// One step. X4 = x of batches 0..3 (f32x4, all lanes). Updates cc; defines
// hv; writes h splits to HOUT. No barrier inside.
#define GCORE(X4, HIN, HOUT)                                           \
    float hv;                                                          \
    {                                                                  \
        const short* hin_ = (HIN);                                     \
        short8 a0 = *(const short8*)(hin_ + ard0);                     \
        short8 a1 = *(const short8*)(hin_ + ard1);                     \
        f32x4 ac0, ac1, ac2, ac3;                                      \
        _Pragma("unroll")                                              \
        for (int r = 0; r < 4; ++r) {                                  \
            ac0[r] = fmaf(wx[0], (X4)[r], bb[0]);                      \
            ac1[r] = fmaf(wx[1], (X4)[r], bb[1]);                      \
            ac2[r] = fmaf(wx[2], (X4)[r], bb[2]);                      \
            ac3[r] = fmaf(wx[3], (X4)[r], bb[3]);                      \
        }                                                              \
        ac0 = MFMA(a0, Bf[0][0][0], ac0);   /* kt0, w_hi */            \
        ac1 = MFMA(a0, Bf[1][0][0], ac1);                              \
        ac2 = MFMA(a0, Bf[2][0][0], ac2);                              \
        ac3 = MFMA(a0, Bf[3][0][0], ac3);                              \
        ac0 = MFMA(a0, Bf[0][0][1], ac0);   /* kt0, w_lo */            \
        ac1 = MFMA(a0, Bf[1][0][1], ac1);                              \
        ac2 = MFMA(a0, Bf[2][0][1], ac2);                              \
        ac3 = MFMA(a0, Bf[3][0][1], ac3);                              \
        ac0 = MFMA(a1, Bf[0][1][0], ac0);   /* kt1, w_hi */            \
        ac1 = MFMA(a1, Bf[1][1][0], ac1);                              \
        ac2 = MFMA(a1, Bf[2][1][0], ac2);                              \
        ac3 = MFMA(a1, Bf[3][1][0], ac3);                              \
        ac0 = MFMA(a1, Bf[0][1][1], ac0);   /* kt1, w_lo */            \
        ac1 = MFMA(a1, Bf[1][1][1], ac1);                              \
        ac2 = MFMA(a1, Bf[2][1][1], ac2);                              \
        ac3 = MFMA(a1, Bf[3][1][1], ac3);                              \
        float s0 = SELS(ac0), s1 = SELS(ac1);                          \
        float s2 = SELS(ac2), s3 = SELS(ac3);                          \
        float p0 = SELK(ac0) + __shfl_xor(s0, 16, 64);                 \
        float p1 = SELK(ac1) + __shfl_xor(s1, 16, 64);                 \
        float p2 = SELK(ac2) + __shfl_xor(s2, 16, 64);                 \
        float p3 = SELK(ac3) + __shfl_xor(s3, 16, 64);                 \
        float vi = sigm2(p0);                                          \
        float vf = sigm2(p1);                                          \
        float vg = fmaf(2.0f, sigm2(p2), -1.0f);                       \
        float vo = sigm2(p3);                                          \
        cc = fmaf(vf, cc, vi * vg);                                    \
        hv = vo * tanhc(cc);                                           \
        unsigned short q0 = f2bf(hv);                                  \
        unsigned short q1 = f2bf(hv - bf2f(q0));                       \
        short* ho_ = (HOUT);                                           \
        ho_[wr0] = (short)q0;                                          \
        ho_[wr1] = (short)q1;                                          \
    }

// Decoder step: GCORE + fc butterfly over nl -> pb[w*4+kg]; barrier;
// every lane rebuilds y4 (all 4 batches); out write; feedback.
#define DSTEP(T, HIN, HOUT, PB)                                        \
    {                                                                  \
        GCORE(xc, HIN, HOUT)                                           \
        float p = fcw * hv;                                            \
        p += __shfl_xor(p, 1, 64);                                     \
        p += __shfl_xor(p, 2, 64);                                     \
        p += __shfl_xor(p, 4, 64);                                     \
        p += __shfl_xor(p, 8, 64);                                     \
        if (nl == 0) (PB)[w * 4 + kg] = p;                             \
        __syncthreads();                                               \
        f32x4 y4 = *(const f32x4*)&(PB)[0];                            \
        y4 += *(const f32x4*)&(PB)[4];                                 \
        y4 += *(const f32x4*)&(PB)[8];                                 \
        y4 += *(const f32x4*)&(PB)[12];                                \
        _Pragma("unroll") for (int r = 0; r < 4; ++r) y4[r] += fb;     \
        if (tid < 4)                                                   \
            out[(size_t)(b0 + tid) * TGT + (T)] =                      \
                (tid == 0) ? y4[0] : (tid == 1) ? y4[1]                \
              : (tid == 2) ? y4[2] : y4[3];                            \
        xc = y4;                                                       \
    }

extern "C" __global__ void __launch_bounds__(256, 2)
seq2seq_kernel(const float* __restrict__ src,
               const float* __restrict__ eWih, const float* __restrict__ eWhh,
               const float* __restrict__ eBih, const float* __restrict__ eBhh,
               const float* __restrict__ dWih, const float* __restrict__ dWhh,
               const float* __restrict__ dBih, const float* __restrict__ dBhh,
               const float* __restrict__ fcW, const float* __restrict__ fcB,
               float* __restrict__ out) {
    const int tid  = threadIdx.x;        // 0..255
    const int lane = tid & 63;
    const int w    = tid >> 6;           // wave 0..3 = unit tile
    const int nl   = lane & 15;          // n-col within tile; also A-row
    const int kg   = lane >> 4;          // k-octet; ALSO this lane's batch
    const bool k1  = (kg & 1), k2 = (kg & 2);
    const int un   = 16 * w + nl;        // this lane's unit
    const int b0   = blockIdx.x * MB;
    // A-frag read offsets: row nl carries (split (nl>>2)&1, batch nl&3)
    const int aspl = (nl >> 2) & 1, abat = nl & 3;
    const int ard0 = HB(aspl, 0, kg) + abat * 8;
    const int ard1 = HB(aspl, 1, kg) + abat * 8;
    // h-write addresses (unit un, batch kg, splits 0/1)
    const int ukt  = un >> 5, uqg = (un >> 3) & 3, uj = un & 7;
    const int wr0  = HB(0, ukt, uqg) + kg * 8 + uj;
    const int wr1  = HB(1, ukt, uqg) + kg * 8 + uj;

    __shared__ __align__(16) short hfA[HFSZ], hfB[HFSZ];  // h splits, dbuf
    __shared__ __align__(16) float srcT[SEQ * MB];        // [t][4 batches]
    __shared__ __align__(16) float pbA[16], pbB[16];      // fc partials [w][b]

    for (int i = tid; i < HFSZ; i += 256) { hfA[i] = 0; hfB[i] = 0; }
    for (int i = tid; i < SEQ * MB; i += 256) {
        int e = i >> 9, t = i & 511;                      // coalesced in t
        srcT[t * MB + e] = src[(size_t)(b0 + e) * SEQ + t];
    }

    short8 Bf[4][2][2];                  // [gate][kt][split] (AGPR-friendly)
    float bb[4], wx[4];
    float cc = 0.0f;                     // cell (batch kg, unit un)

    auto loadW = [&](const float* Wih, const float* Whh,
                     const float* Bih, const float* Bhh) {
#pragma unroll
        for (int g = 0; g < 4; ++g) {
            const float sc = (g == 2) ? 2.0f * L2E : L2E;  // tanh fold
            const bool nv  = (un < HID);
            const int row  = g * HID + (nv ? un : 0);      // PyTorch g*50+u
            // bias + wx*x belong only to the h_hi rows (kg even)
            const float km = k1 ? 0.0f : 1.0f;
            bb[g] = nv ? (Bih[row] + Bhh[row]) * sc * km : 0.0f;
            wx[g] = nv ? Wih[row] * sc * km : 0.0f;
#pragma unroll
            for (int kt = 0; kt < 2; ++kt) {
                short8 s0, s1;
#pragma unroll
                for (int j = 0; j < 8; ++j) {
                    int kk = kt * 32 + kg * 8 + j;
                    float wv = (nv && kk < HID)
                             ? Whh[(size_t)row * HID + kk] * sc : 0.0f;
                    unsigned short h0 = f2bf(wv);
                    unsigned short h1 = f2bf(wv - bf2f(h0));
                    s0[j] = (short)h0; s1[j] = (short)h1;
                }
                Bf[g][kt][0] = s0; Bf[g][kt][1] = s1;
            }
        }
    };

    // ---------------- encoder: 512 steps (x2 unroll) ----------------
    loadW(eWih, eWhh, eBih, eBhh);
    __syncthreads();                     // hf zero + srcT staged
    for (int t = 0; t < SEQ; t += 2) {
        {
            f32x4 xe = *(const f32x4*)&srcT[t * MB];
            GCORE(xe, hfA, hfB)
        }
        __syncthreads();
        {
            f32x4 xe = *(const f32x4*)&srcT[(t + 1) * MB];
            GCORE(xe, hfB, hfA)
        }
        __syncthreads();
    }
    // state in hfA

    // ---------------- decoder: 256 steps (x2 unroll) ----------------
    loadW(dWih, dWhh, dBih, dBhh);
    const float fcw = (un < HID) ? fcW[un] : 0.0f;
    const float fb  = fcB[0];
    f32x4 xc = {0.f, 0.f, 0.f, 0.f};     // decoder_input = zeros
    for (int t = 0; t < TGT; t += 2) {
        DSTEP(t,     hfA, hfB, pbA)
        DSTEP(t + 1, hfB, hfA, pbB)
    }
}

extern "C" void kernel_launch(void* const* d_in, const int* in_sizes, int n_in,
                              void* d_out, int out_size, void* d_ws, size_t ws_size,
                              hipStream_t stream) {
    const float* src  = (const float*)d_in[0];
    const float* eWih = (const float*)d_in[1];
    const float* eWhh = (const float*)d_in[2];
    const float* eBih = (const float*)d_in[3];
    const float* eBhh = (const float*)d_in[4];
    const float* dWih = (const float*)d_in[5];
    const float* dWhh = (const float*)d_in[6];
    const float* dBih = (const float*)d_in[7];
    const float* dBhh = (const float*)d_in[8];
    const float* fcW  = (const float*)d_in[9];
    const float* fcB  = (const float*)d_in[10];
    float* out = (float*)d_out;

    const int B = in_sizes[0] / SEQ;     // 2048
    seq2seq_kernel<<<B / MB, 256, 0, stream>>>(src, eWih, eWhh, eBih, eBhh,
                                               dWih, dWhh, dBih, dBhh,
                                               fcW, fcB, out);
}

// Round 15
// 537.091 us; speedup vs baseline: 1.0215x; 1.0215x over previous
//
#include <hip/hip_runtime.h>

// Seq2Seq LSTM (enc 512 + dec 256 steps), H=50, B=2048, in/out dim 1.
//
// Round-15 = round-13 (champion, 530 us) + PHASE STAGGER. r13/r14 counters
// showed wall = MFMA-busy + VALU-busy exactly (1653 = 931+727): the two
// co-resident blocks per CU run identical step chains and barrier in
// lock-step, so both waves occupy the same pipe at the same time -- pipe
// overlap (sum -> max) never happens. Fix: blocks of the second dispatch
// round (blockIdx >= 256; round-robin XCD dispatch makes block b and b+256
// CU-partners) sleep ~800 cyc ONCE before the loop, offsetting their phase
// by half a step for the entire 768-step run.
//
// Everything else identical to r13: MB=4, 512 blocks = 2/CU, 4 waves/block,
// wave w = units 16w..16w+15, all 4 gates per wave (4 MFMA accumulators),
// row-duplicated A (row m -> batch m>>2) so every lane owns exactly one
// cell (batch kg, unit un) at reg 0 -- no dynamic selects, no shfl in the
// step. 2-way bf16 split, 3 cross terms (absmax 4.9e-4, verified r10-r14).
// One barrier per step. L2E folded into weights/bias.

#define HID 50
#define SEQ 512
#define TGT 256
#define MB  4
#define L2E 1.44269504088896341f

typedef __attribute__((ext_vector_type(8))) short short8;
typedef __attribute__((ext_vector_type(4))) float f32x4;

__device__ __forceinline__ unsigned short f2bf(float f) {   // RNE fp32->bf16
    unsigned u = __float_as_uint(f);
    return (unsigned short)((u + 0x7fffu + ((u >> 16) & 1u)) >> 16);
}
__device__ __forceinline__ float bf2f(unsigned short b) {
    return __uint_as_float(((unsigned)b) << 16);
}
__device__ __forceinline__ float sigm2(float a) {   // a pre-scaled by L2E
    return __builtin_amdgcn_rcpf(1.0f + __builtin_amdgcn_exp2f(-a));
}
__device__ __forceinline__ float tanhc(float c) {   // c in linear domain
    return fmaf(2.0f,
        __builtin_amdgcn_rcpf(1.0f + __builtin_amdgcn_exp2f(-2.0f * L2E * c)),
        -1.0f);
}

#define MFMA(A, B, C) __builtin_amdgcn_mfma_f32_16x16x32_bf16((A), (B), (C), 0, 0, 0)

// h layout: block (split s, k-tile kt, k-octet qg) = 4 batches x 8 k shorts.
#define HB(s, kt, qg) ((((s) * 2 + (kt)) * 4 + (qg)) * 32)
#define HFSZ (2 * 2 * 4 * 32)   // 512 shorts

// One step. XK = x for batch kg. Updates cc; defines hv; writes h splits.
#define GCORE(XK, HIN, HOUT)                                           \
    float hv;                                                          \
    {                                                                  \
        const short* hin_ = (HIN);                                     \
        short8 a00 = *(const short8*)(hin_ + HB(0, 0, kg) + bsel * 8); \
        short8 a01 = *(const short8*)(hin_ + HB(1, 0, kg) + bsel * 8); \
        short8 a10 = *(const short8*)(hin_ + HB(0, 1, kg) + bsel * 8); \
        short8 a11 = *(const short8*)(hin_ + HB(1, 1, kg) + bsel * 8); \
        float i0 = fmaf(wx[0], (XK), bb[0]);                           \
        float i1 = fmaf(wx[1], (XK), bb[1]);                           \
        float i2 = fmaf(wx[2], (XK), bb[2]);                           \
        float i3 = fmaf(wx[3], (XK), bb[3]);                           \
        f32x4 ac0 = {i0, i0, i0, i0};                                  \
        f32x4 ac1 = {i1, i1, i1, i1};                                  \
        f32x4 ac2 = {i2, i2, i2, i2};                                  \
        f32x4 ac3 = {i3, i3, i3, i3};                                  \
        ac0 = MFMA(a00, Bf[0][0][0], ac0);                             \
        ac1 = MFMA(a00, Bf[1][0][0], ac1);                             \
        ac2 = MFMA(a00, Bf[2][0][0], ac2);                             \
        ac3 = MFMA(a00, Bf[3][0][0], ac3);                             \
        ac0 = MFMA(a00, Bf[0][0][1], ac0);                             \
        ac1 = MFMA(a00, Bf[1][0][1], ac1);                             \
        ac2 = MFMA(a00, Bf[2][0][1], ac2);                             \
        ac3 = MFMA(a00, Bf[3][0][1], ac3);                             \
        ac0 = MFMA(a01, Bf[0][0][0], ac0);                             \
        ac1 = MFMA(a01, Bf[1][0][0], ac1);                             \
        ac2 = MFMA(a01, Bf[2][0][0], ac2);                             \
        ac3 = MFMA(a01, Bf[3][0][0], ac3);                             \
        ac0 = MFMA(a10, Bf[0][1][0], ac0);                             \
        ac1 = MFMA(a10, Bf[1][1][0], ac1);                             \
        ac2 = MFMA(a10, Bf[2][1][0], ac2);                             \
        ac3 = MFMA(a10, Bf[3][1][0], ac3);                             \
        ac0 = MFMA(a10, Bf[0][1][1], ac0);                             \
        ac1 = MFMA(a10, Bf[1][1][1], ac1);                             \
        ac2 = MFMA(a10, Bf[2][1][1], ac2);                             \
        ac3 = MFMA(a10, Bf[3][1][1], ac3);                             \
        ac0 = MFMA(a11, Bf[0][1][0], ac0);                             \
        ac1 = MFMA(a11, Bf[1][1][0], ac1);                             \
        ac2 = MFMA(a11, Bf[2][1][0], ac2);                             \
        ac3 = MFMA(a11, Bf[3][1][0], ac3);                             \
        float vi = sigm2(ac0[0]);                                      \
        float vf = sigm2(ac1[0]);                                      \
        float vg = fmaf(2.0f, sigm2(ac2[0]), -1.0f);                   \
        float vo = sigm2(ac3[0]);                                      \
        cc = fmaf(vf, cc, vi * vg);                                    \
        hv = vo * tanhc(cc);                                           \
        unsigned short q0 = f2bf(hv);                                  \
        unsigned short q1 = f2bf(hv - bf2f(q0));                       \
        short* ho_ = (HOUT);                                           \
        ho_[wr0] = (short)q0;                                          \
        ho_[wr1] = (short)q1;                                          \
    }

// Decoder step: GCORE + 16-lane fc butterfly -> pb; barrier; y rebuild in
// every lane; out write; feedback.
#define DSTEP(T, HIN, HOUT, PB)                                        \
    {                                                                  \
        GCORE(xc, HIN, HOUT)                                           \
        float p = fcw * hv;                                            \
        p += __shfl_xor(p, 1, 64);                                     \
        p += __shfl_xor(p, 2, 64);                                     \
        p += __shfl_xor(p, 4, 64);                                     \
        p += __shfl_xor(p, 8, 64);                                     \
        if (nl == 0) (PB)[kg * 4 + w] = p;                             \
        __syncthreads();                                               \
        f32x4 s_ = *(const f32x4*)&(PB)[kg * 4];                       \
        float y = s_[0] + s_[1] + s_[2] + s_[3] + fb;                  \
        if (w == 0 && nl == 0) out[(size_t)(b0 + kg) * TGT + (T)] = y; \
        xc = y;                                                        \
    }

extern "C" __global__ void __launch_bounds__(256, 2)
seq2seq_kernel(const float* __restrict__ src,
               const float* __restrict__ eWih, const float* __restrict__ eWhh,
               const float* __restrict__ eBih, const float* __restrict__ eBhh,
               const float* __restrict__ dWih, const float* __restrict__ dWhh,
               const float* __restrict__ dBih, const float* __restrict__ dBhh,
               const float* __restrict__ fcW, const float* __restrict__ fcB,
               float* __restrict__ out) {
    const int tid  = threadIdx.x;        // 0..255
    const int lane = tid & 63;
    const int w    = tid >> 6;           // wave 0..3 = unit tile
    const int nl   = lane & 15;          // n-col within tile
    const int kg   = lane >> 4;          // k-octet; ALSO this lane's batch
    const int bsel = nl >> 2;            // A-row m -> batch m>>2
    const int un   = 16 * w + nl;        // this lane's unit
    const int b0   = blockIdx.x * MB;
    const int ukt  = un >> 5, uqg = (un >> 3) & 3, uj = un & 7;
    const int wr0  = HB(0, ukt, uqg) + kg * 8 + uj;   // h split-0 write
    const int wr1  = HB(1, ukt, uqg) + kg * 8 + uj;   // h split-1 write

    __shared__ __align__(16) short hfA[HFSZ], hfB[HFSZ];  // h splits, dbuf
    __shared__ __align__(16) float srcT[SEQ * MB];        // [t][4 batches]
    __shared__ __align__(16) float pbA[16], pbB[16];      // fc partials [b][w]

    for (int i = tid; i < HFSZ; i += 256) { hfA[i] = 0; hfB[i] = 0; }
    for (int i = tid; i < SEQ * MB; i += 256) {
        int e = i >> 9, t = i & 511;                      // coalesced in t
        srcT[t * MB + e] = src[(size_t)(b0 + e) * SEQ + t];
    }

    short8 Bf[4][2][2];                  // [gate][kt][split] (AGPR-friendly)
    float bb[4], wx[4];
    float cc = 0.0f;                     // cell (batch kg, unit un)

    auto loadW = [&](const float* Wih, const float* Whh,
                     const float* Bih, const float* Bhh) {
#pragma unroll
        for (int g = 0; g < 4; ++g) {
            const float sc = (g == 2) ? 2.0f * L2E : L2E;  // tanh fold
            const bool nv  = (un < HID);
            const int row  = g * HID + (nv ? un : 0);      // PyTorch g*50+u
            bb[g] = nv ? (Bih[row] + Bhh[row]) * sc : 0.0f;
            wx[g] = nv ? Wih[row] * sc : 0.0f;
#pragma unroll
            for (int kt = 0; kt < 2; ++kt) {
                short8 s0, s1;
#pragma unroll
                for (int j = 0; j < 8; ++j) {
                    int kk = kt * 32 + kg * 8 + j;
                    float wv = (nv && kk < HID)
                             ? Whh[(size_t)row * HID + kk] * sc : 0.0f;
                    unsigned short h0 = f2bf(wv);
                    unsigned short h1 = f2bf(wv - bf2f(h0));
                    s0[j] = (short)h0; s1[j] = (short)h1;
                }
                Bf[g][kt][0] = s0; Bf[g][kt][1] = s1;
            }
        }
    };

    // ---------------- encoder: 512 steps (x2 unroll) ----------------
    loadW(eWih, eWhh, eBih, eBhh);
    __syncthreads();                     // hf zero + srcT staged

    // PHASE STAGGER: second dispatch round (the CU-partner block under
    // round-robin XCD dispatch) starts ~800 cyc late, de-phasing the two
    // co-resident blocks so one's MFMA phase overlaps the other's VALU
    // phase for the whole run. One-time, deterministic, graph-safe.
    if (blockIdx.x >= 256) {
        __builtin_amdgcn_s_sleep(12);    // ~12*64 = 768 cyc
    }

    for (int t = 0; t < SEQ; t += 2) {
        { GCORE(srcT[t * MB + kg], hfA, hfB) }
        __syncthreads();
        { GCORE(srcT[(t + 1) * MB + kg], hfB, hfA) }
        __syncthreads();
    }
    // state in hfA

    // ---------------- decoder: 256 steps (x2 unroll) ----------------
    loadW(dWih, dWhh, dBih, dBhh);
    const float fcw = (un < HID) ? fcW[un] : 0.0f;
    const float fb  = fcB[0];
    float xc = 0.0f;                     // decoder_input = zeros
    for (int t = 0; t < TGT; t += 2) {
        DSTEP(t,     hfA, hfB, pbA)
        DSTEP(t + 1, hfB, hfA, pbB)
    }
}

extern "C" void kernel_launch(void* const* d_in, const int* in_sizes, int n_in,
                              void* d_out, int out_size, void* d_ws, size_t ws_size,
                              hipStream_t stream) {
    const float* src  = (const float*)d_in[0];
    const float* eWih = (const float*)d_in[1];
    const float* eWhh = (const float*)d_in[2];
    const float* eBih = (const float*)d_in[3];
    const float* eBhh = (const float*)d_in[4];
    const float* dWih = (const float*)d_in[5];
    const float* dWhh = (const float*)d_in[6];
    const float* dBih = (const float*)d_in[7];
    const float* dBhh = (const float*)d_in[8];
    const float* fcW  = (const float*)d_in[9];
    const float* fcB  = (const float*)d_in[10];
    float* out = (float*)d_out;

    const int B = in_sizes[0] / SEQ;     // 2048
    seq2seq_kernel<<<B / MB, 256, 0, stream>>>(src, eWih, eWhh, eBih, eBhh,
                                               dWih, dWhh, dBih, dBhh,
                                               fcW, fcB, out);
}